// Round 9
// baseline (7643.888 us; speedup 1.0000x reference)
//
#include <hip/hip_runtime.h>
#include <math.h>

#define SEQ   512
#define BATCH 64
#define HID   512
#define NROW  1536                     // 3 gates * HID rows
#define XROW_FLOATS ((size_t)SEQ * NROW * BATCH)   // 201.3 MB
#define HBUF_QWORDS (2 * BATCH * HID)              // double-buffered tagged h, u64 [parity][b][j]
#define NCNT  (SEQ * 6)                // per-(t, 256-row unit) completion counters
#define SBH ((size_t)SEQ * BATCH * HID)

__device__ __forceinline__ float sigf(float x) {
    return 1.f / (1.f + __expf(-x));
}
__device__ __forceinline__ float tanh_fast(float x) {
    float ax = fabsf(x);
    float e = __expf(-2.f * ax);
    float r = (1.f - e) / (1.f + e);
    return copysignf(r, x);
}
// butterfly add via DPP (VALU pipe, not LDS); ctrl is a template constant.
template <int CTRL>
__device__ __forceinline__ float dpp_add(float v) {
    int x = __builtin_amdgcn_update_dpp(0, __builtin_bit_cast(int, v),
                                        CTRL, 0xf, 0xf, true);
    return v + __builtin_bit_cast(float, x);
}

// ---------------- Fused kernel: scan wgs (0..255) + xproj wgs (256..511) ----------------
// r8 insight: xproj (~1960us) and scan (~2850us) were SERIAL, but the scan is
// latency-bound at VALUBusy 35% -- 65% of issue slots idle, 8 of 32 waves/CU
// used. Fuse: 512 co-resident wgs (launch_bounds (512,4) caps VGPR at 128 ->
// 2 wgs/CU guaranteed -> no deadlock, full co-residency). xproj units are
// t-major so early timesteps appear within ~1 unit (~30-80us); after that,
// production stays ahead of the scan's 5.6us/step consumption.
// xrow handoff = the r0-proven protocol: agent-relaxed stores (MALL-visible),
// per-wave s_waitcnt(0), then a per-unit counter bump; consumers poll the
// counter (==4 waves) then agent-load the data.
#define HPAD 10                        // h LDS row stride (2-way = free, 8B-aligned)
#define H_FLOATS (512 * HPAD)          // 5120
__global__ __launch_bounds__(512, 4) void fused_kernel(
    const float* __restrict__ x,
    const float* __restrict__ Wxi, const float* __restrict__ Wxc, const float* __restrict__ Wxo,
    const float* __restrict__ Whi, const float* __restrict__ Whc, const float* __restrict__ Who,
    const float* __restrict__ bi, const float* __restrict__ bc, const float* __restrict__ bo,
    float* __restrict__ xrow, unsigned long long* __restrict__ hbuf,
    unsigned* __restrict__ cnt, float* __restrict__ out)
{
    extern __shared__ float lds[];
    const int tid = threadIdx.x;

    if (blockIdx.x >= 256) {
        // ================= xproj role =================
        // 512 teams of 4 waves; unit = (t, s) = 256 rows x 64 batches.
        // u = teamid + 512*round (round<6): round 0 covers t=0..85.
        const int xwg  = blockIdx.x - 256;
        const int wv   = tid >> 6, lane = tid & 63;
        const int tm   = wv >> 2,  twv  = wv & 3;     // team 0..1, wave-in-team 0..3
        const int teamid = xwg * 2 + tm;              // 0..511
        const int bq = lane & 15, rq = lane >> 4;

        for (int round = 0; round < 6; ++round) {
            const int u = teamid + 512 * round;       // 0..3071
            const int t = u / 6, s = u - 6 * t;       // s 0..5 (unit rows s*256..+255)
            const float* xb = x + ((size_t)t * 64 + 4 * bq) * 512;

            for (int half = 0; half < 2; ++half) {
                const int R0 = s * 256 + half * 128 + twv * 32 + rq * 8;  // single gate
                const int g = R0 >> 9, j0 = R0 & 511;
                const float* wsrc = (g == 0) ? Wxi : ((g == 1) ? Wxc : Wxo);
                const float* wp = wsrc + (size_t)j0 * 512;

                float acc[8][4];
                #pragma unroll
                for (int r = 0; r < 8; ++r)
                    #pragma unroll
                    for (int j = 0; j < 4; ++j) acc[r][j] = 0.f;

                for (int k4 = 0; k4 < 128; ++k4) {
                    float4 xv[4];
                    #pragma unroll
                    for (int j = 0; j < 4; ++j)
                        xv[j] = *(const float4*)(xb + j * 512 + k4 * 4);
                    #pragma unroll
                    for (int r = 0; r < 8; ++r) {
                        const float4 w4 = *(const float4*)(wp + (size_t)r * 512 + k4 * 4);
                        #pragma unroll
                        for (int j = 0; j < 4; ++j)
                            acc[r][j] += w4.x * xv[j].x + w4.y * xv[j].y
                                       + w4.z * xv[j].z + w4.w * xv[j].w;
                    }
                }
                // agent-scope stores -> visible at MALL (bypass non-coherent L2)
                #pragma unroll
                for (int r = 0; r < 8; ++r) {
                    const size_t base = ((size_t)t * NROW + R0 + r) * 64 + 4 * bq;
                    const unsigned long long p0 =
                        ((unsigned long long)__builtin_bit_cast(unsigned, acc[r][1]) << 32) |
                        __builtin_bit_cast(unsigned, acc[r][0]);
                    const unsigned long long p1 =
                        ((unsigned long long)__builtin_bit_cast(unsigned, acc[r][3]) << 32) |
                        __builtin_bit_cast(unsigned, acc[r][2]);
                    __hip_atomic_store((unsigned long long*)(xrow + base), p0,
                                       __ATOMIC_RELAXED, __HIP_MEMORY_SCOPE_AGENT);
                    __hip_atomic_store((unsigned long long*)(xrow + base) + 1, p1,
                                       __ATOMIC_RELAXED, __HIP_MEMORY_SCOPE_AGENT);
                }
            }
            // drain this wave's stores, then bump the unit counter (target 4)
            __builtin_amdgcn_s_waitcnt(0);
            if (lane == 0)
                __hip_atomic_fetch_add(cnt + t * 6 + s, 1u,
                                       __ATOMIC_RELAXED, __HIP_MEMORY_SCOPE_AGENT);
        }
        return;
    }

    // ================= scan role (r6 frozen + tagged-xrow read) =================
    float* hlds = lds;                         // [512 k][10] b in 0..7
    float* gbuf = lds + H_FLOATS;              // [48 rho][8 b]
    float* biasL = gbuf + 384;                 // [48]

    const int lane = tid & 63;
    const int gid = blockIdx.x & 7;            // batch group
    const int m   = blockIdx.x >> 3;           // j-slice member 0..31
    const int rg  = tid >> 5, ks = tid & 31;   // GEMM coords (rg in 0..15)

    // ---- one-time: recurrent weights into registers ----
    float w3r[16][3];
    #pragma unroll
    for (int r = 0; r < 3; ++r) {
        const int rho = rg * 3 + r;
        const int g = rho >> 4, jloc = rho & 15;
        const float* wsrc = (g == 0) ? Whi : ((g == 1) ? Whc : Who);
        const float* wp = wsrc + (size_t)(m * 16 + jloc) * 512 + ks;
        #pragma unroll
        for (int i = 0; i < 16; ++i) w3r[i][r] = wp[32 * i];
    }
    if (tid < 48) {
        const int g = tid >> 4, jloc = tid & 15;
        const float* bb = (g == 0) ? bi : ((g == 1) ? bc : bo);
        biasL[tid] = bb[m * 16 + jloc];
    }

    // epilogue identity (tid < 128): j-fastest for coalesced global stores
    const int ejl = tid & 15, eb = tid >> 4;
    const int jg  = m * 16 + ejl;              // global j
    const int bg  = gid * 8 + eb;              // global batch
    const int s0  = m >> 4;                    // xrow unit slice (wg-uniform)
    float creg = 0.f;

    if (tid < 128) hlds[jg * HPAD + eb] = 0.f;
    __syncthreads();

    const bool own_k = ((tid >> 4) == m);      // k in our own j-slice

    for (int t = 0; t < SEQ; ++t) {
        // ---- (A) issue hbuf staging loads (independent of xrow) ----
        const unsigned long long* hsrc =
            hbuf + (size_t)(t & 1) * (BATCH * HID) + (size_t)gid * 8 * 512 + tid;
        unsigned long long hv[8];
        if (!own_k) {
            #pragma unroll
            for (int q = 0; q < 8; ++q)
                hv[q] = __hip_atomic_load(hsrc + (size_t)q * 512, __ATOMIC_RELAXED,
                                          __HIP_MEMORY_SCOPE_AGENT);
        }

        // ---- (B) xrow tag poll + xr loads (tid < 128; overlaps staging) ----
        float xr0 = 0.f, xr1 = 0.f, xr2 = 0.f;
        if (tid < 128) {
            const unsigned* cb = cnt + t * 6 + s0;
            unsigned c0 = __hip_atomic_load(cb,     __ATOMIC_RELAXED, __HIP_MEMORY_SCOPE_AGENT);
            unsigned c1 = __hip_atomic_load(cb + 2, __ATOMIC_RELAXED, __HIP_MEMORY_SCOPE_AGENT);
            unsigned c2 = __hip_atomic_load(cb + 4, __ATOMIC_RELAXED, __HIP_MEMORY_SCOPE_AGENT);
            while (!(c0 >= 4u && c1 >= 4u && c2 >= 4u)) {
                c0 = __hip_atomic_load(cb,     __ATOMIC_RELAXED, __HIP_MEMORY_SCOPE_AGENT);
                c1 = __hip_atomic_load(cb + 2, __ATOMIC_RELAXED, __HIP_MEMORY_SCOPE_AGENT);
                c2 = __hip_atomic_load(cb + 4, __ATOMIC_RELAXED, __HIP_MEMORY_SCOPE_AGENT);
                __builtin_amdgcn_s_sleep(1);
            }
            const size_t base = ((size_t)t * NROW + jg) * 64 + bg;
            xr0 = __builtin_bit_cast(float, __hip_atomic_load(
                (const unsigned*)xrow + base, __ATOMIC_RELAXED, __HIP_MEMORY_SCOPE_AGENT));
            xr1 = __builtin_bit_cast(float, __hip_atomic_load(
                (const unsigned*)xrow + base + (size_t)512 * 64, __ATOMIC_RELAXED, __HIP_MEMORY_SCOPE_AGENT));
            xr2 = __builtin_bit_cast(float, __hip_atomic_load(
                (const unsigned*)xrow + base + (size_t)1024 * 64, __ATOMIC_RELAXED, __HIP_MEMORY_SCOPE_AGENT));
        }

        // ---- (C) hbuf poll-in-place; own k-range comes via LDS ----
        if (!own_k) {
            const unsigned tgt = (unsigned)t;
            unsigned pend = 0xffu;
            while (pend) {
                unsigned np = 0;
                #pragma unroll
                for (int q = 0; q < 8; ++q) {
                    if ((pend >> q) & 1) {
                        if ((unsigned)(hv[q] >> 32) >= tgt) {
                            hlds[tid * HPAD + q] =
                                __builtin_bit_cast(float, (unsigned)hv[q]);
                        } else np |= 1u << q;
                    }
                }
                if (np) {
                    #pragma unroll
                    for (int q = 0; q < 8; ++q)
                        if ((np >> q) & 1)
                            hv[q] = __hip_atomic_load(hsrc + (size_t)q * 512,
                                                      __ATOMIC_RELAXED,
                                                      __HIP_MEMORY_SCOPE_AGENT);
                    __builtin_amdgcn_s_sleep(1);
                }
                pend = np;
            }
        }
        __syncthreads();

        // ---- GEMM: acc[r][b] = sum_k w3r[i][r] * h[k][b], k = ks+32i ----
        float acc[3][8];
        #pragma unroll
        for (int r = 0; r < 3; ++r)
            #pragma unroll
            for (int b = 0; b < 8; ++b) acc[r][b] = 0.f;

        {
            const float* hb = hlds + ks * HPAD;
            #pragma unroll
            for (int i = 0; i < 16; ++i) {
                float hv2[8];
                *(float2*)&hv2[0] = *(const float2*)(hb + i * (32 * HPAD) + 0);
                *(float2*)&hv2[2] = *(const float2*)(hb + i * (32 * HPAD) + 2);
                *(float2*)&hv2[4] = *(const float2*)(hb + i * (32 * HPAD) + 4);
                *(float2*)&hv2[6] = *(const float2*)(hb + i * (32 * HPAD) + 6);
                #pragma unroll
                for (int r = 0; r < 3; ++r)
                    #pragma unroll
                    for (int b = 0; b < 8; ++b)
                        acc[r][b] += w3r[i][r] * hv2[b];
            }
            // ---- reduce over ks on the VALU pipe ----
            #pragma unroll
            for (int r = 0; r < 3; ++r)
                #pragma unroll
                for (int b = 0; b < 8; ++b) {
                    float v = acc[r][b];
                    v = dpp_add<0x121>(v);  // row_ror:1
                    v = dpp_add<0x122>(v);  // row_ror:2
                    v = dpp_add<0x124>(v);  // row_ror:4
                    v = dpp_add<0x128>(v);  // row_ror:8
                    v = dpp_add<0x142>(v);  // row_bcast15 -> lanes 16..31/48..63
                    acc[r][b] = v;
                }
            if (lane == 16 || lane == 48) {
                #pragma unroll
                for (int r = 0; r < 3; ++r) {
                    float* gp = gbuf + (rg * 3 + r) * 8;
                    *(float4*)gp       = make_float4(acc[r][0], acc[r][1], acc[r][2], acc[r][3]);
                    *(float4*)(gp + 4) = make_float4(acc[r][4], acc[r][5], acc[r][6], acc[r][7]);
                }
            }
        }
        __syncthreads();

        // ---- elementwise update (tid < 128): thread = (eb, ejl); publish tagged h ----
        if (tid < 128) {
            const float pi = xr0 + biasL[ejl]      + gbuf[(0 * 16 + ejl) * 8 + eb];
            const float pc = xr1 + biasL[16 + ejl] + gbuf[(1 * 16 + ejl) * 8 + eb];
            const float po = xr2 + biasL[32 + ejl] + gbuf[(2 * 16 + ejl) * 8 + eb];
            const float it = sigf(pi);
            const float ch = tanh_fast(pc);
            const float ot = sigf(po);
            creg = (1.f - it) * creg + it * ch;       // coupled forget gate
            const float hn = ot * tanh_fast(creg);
            const unsigned long long pv =
                ((unsigned long long)(unsigned)(t + 1) << 32) |
                (unsigned long long)__builtin_bit_cast(unsigned, hn);
            __hip_atomic_store(hbuf + (size_t)((t + 1) & 1) * (BATCH * HID)
                                    + (size_t)bg * 512 + jg,
                               pv, __ATOMIC_RELAXED, __HIP_MEMORY_SCOPE_AGENT);
            hlds[jg * HPAD + eb] = hn;                // self-bypass for next step
            out[((size_t)t * 64 + bg) * 512 + jg] = hn;
            if (t == SEQ - 1) {
                out[SBH + (size_t)bg * 512 + jg] = hn;             // h_T
                out[SBH + 32768 + (size_t)bg * 512 + jg] = creg;   // c_T
            }
        }
    }
}

extern "C" void kernel_launch(void* const* d_in, const int* in_sizes, int n_in,
                              void* d_out, int out_size, void* d_ws, size_t ws_size,
                              hipStream_t stream)
{
    const float* x   = (const float*)d_in[0];
    const float* Wxi = (const float*)d_in[1];
    const float* Whi = (const float*)d_in[2];
    const float* bi  = (const float*)d_in[3];
    const float* Wxc = (const float*)d_in[4];
    const float* Whc = (const float*)d_in[5];
    const float* bc  = (const float*)d_in[6];
    const float* Wxo = (const float*)d_in[7];
    const float* Who = (const float*)d_in[8];
    const float* bo  = (const float*)d_in[9];
    float* out = (float*)d_out;
    char* ws = (char*)d_ws;

    float*              xrow = (float*)ws;
    unsigned long long* hbuf = (unsigned long long*)(ws + XROW_FLOATS * 4);
    unsigned*           cnt  = (unsigned*)(ws + XROW_FLOATS * 4 + (size_t)HBUF_QWORDS * 8);

    // zero tagged h double-buffer (h_0 = 0, tag 0) + xrow unit counters
    (void)hipMemsetAsync(hbuf, 0, (size_t)HBUF_QWORDS * 8 + (size_t)NCNT * 4, stream);

    // single fused launch: 256 scan wgs + 256 xproj wgs, all co-resident
    // LDS: h 5120 + gbuf 384 + bias 48 = 5552 floats = 22208 B
    hipLaunchKernelGGL(fused_kernel, dim3(512), dim3(512), 22208, stream,
                       x, Wxi, Wxc, Wxo, Whi, Whc, Who, bi, bc, bo,
                       xrow, hbuf, cnt, out);
}